// Round 8
// baseline (155.257 us; speedup 1.0000x reference)
//
#include <hip/hip_runtime.h>

// StereoCostVolume: c1, warp [B=8, H=192, W=640, C=64] f32.
// out [B,H,W,69]: out[...,0:64] = c1; out[...,64+d] = mean_c(c1[w] * warp[w+d-2]), zero-padded in W.
//
// R8: wave-autonomous, NO LDS AT ALL, no barriers of any kind.
// Each wave owns 8 consecutive 8-pixel pairs (64 px) in one row.
//   lane = (px = l>>4, c4 = l&15).
// Per iteration: 12 coalesced float4 loads (2 c1 + 10 warp), 10 dot4 + DPP
// row_shl 16-lane reductions, then DIRECT register stores:
//   - lane (px,c4) stores its c1 float4 at float index pix*69 + c4*4
//     (global_store_dwordx4 needs only 4B alignment; 16-lane group = contiguous
//      256B chunk; L2 write-back merges lines -> no write amplification).
//   - c4==0 lanes store the 5 cost floats (dwordx4 + dword).
// X/Y register double-buffer with NOTHING blocking load hoisting -> compiler
// can hold both fragment sets (~24 loads) in flight per wave.
// Cache policy (R5-R7 evidence: FETCH ~253MB = one input; other stays L3-resident):
// nontemporal c1 loads; plain warp loads; plain out stores (merge in L2;
// R3 showed normal stores don't break warp L3 residency).

typedef float f32x4  __attribute__((ext_vector_type(4)));
typedef float f32x4u __attribute__((ext_vector_type(4), aligned(4)));

#define WIDTH 640
#define CH 64
#define NOFF 5
#define OUTC 69
#define NPIX (8 * 192 * 640)             // 983040
#define NPAIR (NPIX / 8)                 // 122880 pairs (8 px each)
#define NITER 8                          // pairs per wave
#define BDIM 256
#define WPB (BDIM / 64)                  // 4 waves/block
#define NBLOCKS (NPAIR / (WPB * NITER))  // 3840
#define PAIRS_PER_ROW (WIDTH / 8)        // 80 (multiple of NITER -> no row straddle)

__device__ __forceinline__ float row_reduce_sum16_lane0(float v) {
    union { float f; int i; } a, b;
    a.f = v;
    // row_shl:N (0x100+N): lane i reads lane i+N within its 16-lane row (OOB -> 0).
    b.i = __builtin_amdgcn_update_dpp(0, a.i, 0x101, 0xF, 0xF, true); a.f += b.f;
    b.i = __builtin_amdgcn_update_dpp(0, a.i, 0x102, 0xF, 0xF, true); a.f += b.f;
    b.i = __builtin_amdgcn_update_dpp(0, a.i, 0x104, 0xF, 0xF, true); a.f += b.f;
    b.i = __builtin_amdgcn_update_dpp(0, a.i, 0x108, 0xF, 0xF, true); a.f += b.f;
    return a.f;  // lane 0 of each 16-lane row holds the full 16-lane sum
}

struct Frag {
    f32x4 a0, a1;
    f32x4 b0[NOFF], b1[NOFF];
};

__global__ __launch_bounds__(BDIM) void StereoCostVolume_kernel(
    const float* __restrict__ c1,
    const float* __restrict__ warp,
    float* __restrict__ out)
{
    const int t   = threadIdx.x;
    const int wid = t >> 6;
    const int l   = t & 63;
    const int px  = l >> 4;
    const int c4  = l & 15;

    const f32x4* c1f4   = (const f32x4*)c1;
    const f32x4* warpf4 = (const f32x4*)warp;

    const int wave  = blockIdx.x * WPB + wid;
    const int pbase = wave * NITER;                 // first pair
    const int rp0   = pbase % PAIRS_PER_ROW;        // in-row pair idx of iter 0 (multiple of 8)
    const bool leftw  = (rp0 == 0);
    const bool rightw = (rp0 == PAIRS_PER_ROW - NITER);

    const int base0 = (pbase * 8 + px) * 16 + c4;   // f4 idx into c1 AND warp, iter 0 group 0

    auto LOAD = [&](int it, Frag& F) {
        const int base = base0 + it * 128;
        F.a0 = __builtin_nontemporal_load(&c1f4[base]);
        F.a1 = __builtin_nontemporal_load(&c1f4[base + 64]);
        const bool edge = (leftw && it == 0) || (rightw && it == NITER - 1);
        if (!edge) {
            #pragma unroll
            for (int d = 0; d < NOFF; ++d) {
                F.b0[d] = warpf4[base + (d - 2) * 16];
                F.b1[d] = warpf4[base + 64 + (d - 2) * 16];
            }
        } else {
            const int w0 = (rp0 + it) * 8 + px;     // lane width coord, group 0
            #pragma unroll
            for (int d = 0; d < NOFF; ++d) {
                const int ww0 = w0 + d - 2;
                const int ww1 = ww0 + 4;
                F.b0[d] = (ww0 >= 0 && ww0 < WIDTH) ? warpf4[base + (d - 2) * 16]
                                                    : f32x4{0.f, 0.f, 0.f, 0.f};
                F.b1[d] = (ww1 >= 0 && ww1 < WIDTH) ? warpf4[base + 64 + (d - 2) * 16]
                                                    : f32x4{0.f, 0.f, 0.f, 0.f};
            }
        }
    };

    auto PROC = [&](int it, const Frag& F) {
        float s0[NOFF], s1[NOFF];
        #pragma unroll
        for (int d = 0; d < NOFF; ++d) {
            const float acc0 = F.a0.x * F.b0[d].x + F.a0.y * F.b0[d].y
                             + F.a0.z * F.b0[d].z + F.a0.w * F.b0[d].w;
            const float acc1 = F.a1.x * F.b1[d].x + F.a1.y * F.b1[d].y
                             + F.a1.z * F.b1[d].z + F.a1.w * F.b1[d].w;
            s0[d] = row_reduce_sum16_lane0(acc0);
            s1[d] = row_reduce_sum16_lane0(acc1);
        }
        const int pix0 = (pbase + it) * 8 + px;     // group-0 pixel of this lane
        // c1 passthrough: direct 4B-aligned float4 stores (contiguous 256B per 16-lane group)
        *(f32x4u*)(out + pix0 * OUTC + c4 * 4)            = F.a0;
        *(f32x4u*)(out + (pix0 + 4) * OUTC + c4 * 4)      = F.a1;
        // cost channels: lane c4==0 of each row stores 5 floats (x4 + x1)
        if (c4 == 0) {
            f32x4 v0 = { s0[0] * 0.015625f, s0[1] * 0.015625f,
                         s0[2] * 0.015625f, s0[3] * 0.015625f };
            f32x4 v1 = { s1[0] * 0.015625f, s1[1] * 0.015625f,
                         s1[2] * 0.015625f, s1[3] * 0.015625f };
            *(f32x4u*)(out + pix0 * OUTC + CH)       = v0;
            out[pix0 * OUTC + CH + 4]                = s0[4] * 0.015625f;
            *(f32x4u*)(out + (pix0 + 4) * OUTC + CH) = v1;
            out[(pix0 + 4) * OUTC + CH + 4]          = s1[4] * 0.015625f;
        }
    };

    Frag X, Y;
    LOAD(0, X);
    #pragma unroll
    for (int ii = 0; ii < NITER; ii += 2) {
        LOAD(ii + 1, Y);
        PROC(ii, X);
        if (ii + 2 < NITER) LOAD(ii + 2, X);
        PROC(ii + 1, Y);
    }
}

extern "C" void kernel_launch(void* const* d_in, const int* in_sizes, int n_in,
                              void* d_out, int out_size, void* d_ws, size_t ws_size,
                              hipStream_t stream) {
    const float* c1   = (const float*)d_in[0];
    const float* warp = (const float*)d_in[1];
    float* out = (float*)d_out;

    StereoCostVolume_kernel<<<NBLOCKS, BDIM, 0, stream>>>(c1, warp, out);
}

// Round 9
// 144.787 us; speedup vs baseline: 1.0723x; 1.0723x over previous
//
#include <hip/hip_runtime.h>

// StereoCostVolume: c1, warp [B=8, H=192, W=640, C=64] f32.
// out [B,H,W,69]: out[...,0:64] = c1; out[...,64+d] = mean_c(c1[w] * warp[w+d-2]), zero-padded in W.
//
// R9 = R7 structure (wave-autonomous, LDS-bounced coalesced stores, zero block
// barriers) + HAND-PIPELINED loads via inline asm + counted vmcnt (T4/m218):
//   - 12 global_load_dwordx4 per pair issued as asm volatile -> compiler CANNOT
//     sink them into the consuming iteration (R7/R8 post-mortem: VGPR=52-56
//     proved the C++ double-buffer was being folded; latency fully exposed).
//   - s_waitcnt vmcnt(N) with N counted so next pair's 12 loads stay in flight
//     across the current pair's compute+store. In-order vmcnt semantics:
//     steady keep = 4 stores(i-1) + 12 loads(i+1) = 16; prologue 12; tail 4.
//   - "memory" clobber pins stores above each wait; sched_barrier(0) after the
//     wait pins consumers below it (rule #18).
//   - Edge iters (wave-uniform: it==0 left / it==7 right) load from CLAMPED
//     per-lane addresses (always in-bounds), same 12-load count, OOB fragments
//     zeroed by per-lane selects in PROC.
// Store path: R7's private per-wave LDS record bounce -> linear 16B-aligned
// nt float4 stores (R8 showed direct 4B-aligned strided stores cost +30us).

typedef float f32x4 __attribute__((ext_vector_type(4)));

#define WIDTH 640
#define CH 64
#define NOFF 5
#define OUTC 69
#define REC_F4 69                        // float4 per 4-pixel record (1104 B)
#define NPIX (8 * 192 * 640)             // 983040
#define NPAIR (NPIX / 8)                 // 122880 pairs (8 px each)
#define NITER 8                          // pairs per wave
#define BDIM 256
#define WPB (BDIM / 64)                  // 4 waves/block
#define NBLOCKS (NPAIR / (WPB * NITER))  // 3840
#define PAIRS_PER_ROW (WIDTH / 8)        // 80 (multiple of NITER -> no row straddle)

#define WAITV(N) do { \
    asm volatile("s_waitcnt vmcnt(" #N ")" ::: "memory"); \
    __builtin_amdgcn_sched_barrier(0); \
} while (0)

__device__ __forceinline__ float row_reduce_sum16_lane0(float v) {
    union { float f; int i; } a, b;
    a.f = v;
    // row_shl:N (0x100+N): lane i reads lane i+N within its 16-lane row (OOB -> 0).
    b.i = __builtin_amdgcn_update_dpp(0, a.i, 0x101, 0xF, 0xF, true); a.f += b.f;
    b.i = __builtin_amdgcn_update_dpp(0, a.i, 0x102, 0xF, 0xF, true); a.f += b.f;
    b.i = __builtin_amdgcn_update_dpp(0, a.i, 0x104, 0xF, 0xF, true); a.f += b.f;
    b.i = __builtin_amdgcn_update_dpp(0, a.i, 0x108, 0xF, 0xF, true); a.f += b.f;
    return a.f;  // lane 0 of each 16-lane row holds the full 16-lane sum
}

struct Frag {
    f32x4 a0, a1;
    f32x4 b0[NOFF], b1[NOFF];
};

__global__ __launch_bounds__(BDIM) void StereoCostVolume_kernel(
    const float* __restrict__ c1,
    const float* __restrict__ warp,
    float* __restrict__ out)
{
    __shared__ f32x4 lds[WPB * 2 * REC_F4];   // 8832 B/block

    const int t   = threadIdx.x;
    const int wid = t >> 6;
    const int l   = t & 63;
    const int px  = l >> 4;
    const int c4  = l & 15;

    const f32x4* c1f4   = (const f32x4*)c1;
    const f32x4* warpf4 = (const f32x4*)warp;
    f32x4*       outf4  = (f32x4*)out;

    const int wave  = blockIdx.x * WPB + wid;
    const int pbase = wave * NITER;                 // first pair
    const int rp0   = pbase % PAIRS_PER_ROW;        // in-row pair idx (multiple of 8)
    const bool leftw  = (rp0 == 0);
    const bool rightw = (rp0 == PAIRS_PER_ROW - NITER);

    const int base0 = (pbase * 8 + px) * 16 + c4;   // f4 idx into c1 AND warp, iter0 group0

    float* rec0w = (float*)&lds[(wid * 2 + 0) * REC_F4];
    float* rec1w = (float*)&lds[(wid * 2 + 1) * REC_F4];
    const f32x4* rec0r = (const f32x4*)rec0w;
    const f32x4* rec1r = (const f32x4*)rec1w;

    auto LOAD = [&](int it, Frag& F) {
        const char* cb = (const char*)(c1f4 + base0 + it * 128);
        const char* wb = (const char*)(warpf4 + base0 + it * 128);
        asm volatile("global_load_dwordx4 %0, %1, off"             : "=v"(F.a0) : "v"(cb));
        asm volatile("global_load_dwordx4 %0, %1, off offset:1024" : "=v"(F.a1) : "v"(cb));
        const bool edge = (leftw && it == 0) || (rightw && it == NITER - 1);
        if (!edge) {
            asm volatile("global_load_dwordx4 %0, %1, off offset:-512" : "=v"(F.b0[0]) : "v"(wb));
            asm volatile("global_load_dwordx4 %0, %1, off offset:-256" : "=v"(F.b0[1]) : "v"(wb));
            asm volatile("global_load_dwordx4 %0, %1, off"             : "=v"(F.b0[2]) : "v"(wb));
            asm volatile("global_load_dwordx4 %0, %1, off offset:256"  : "=v"(F.b0[3]) : "v"(wb));
            asm volatile("global_load_dwordx4 %0, %1, off offset:512"  : "=v"(F.b0[4]) : "v"(wb));
            asm volatile("global_load_dwordx4 %0, %1, off offset:512"  : "=v"(F.b1[0]) : "v"(wb));
            asm volatile("global_load_dwordx4 %0, %1, off offset:768"  : "=v"(F.b1[1]) : "v"(wb));
            asm volatile("global_load_dwordx4 %0, %1, off offset:1024" : "=v"(F.b1[2]) : "v"(wb));
            asm volatile("global_load_dwordx4 %0, %1, off offset:1280" : "=v"(F.b1[3]) : "v"(wb));
            asm volatile("global_load_dwordx4 %0, %1, off offset:1536" : "=v"(F.b1[4]) : "v"(wb));
        } else {
            // per-lane CLAMPED addresses (always in-bounds); OOB data zeroed in PROC
            const int w0 = (rp0 + it) * 8 + px;
            #pragma unroll
            for (int d = 0; d < NOFF; ++d) {
                const int ww0 = w0 + d - 2;
                const int ww1 = ww0 + 4;
                const int cl0 = ww0 < 0 ? 0 : (ww0 >= WIDTH ? WIDTH - 1 : ww0);
                const int cl1 = ww1 < 0 ? 0 : (ww1 >= WIDTH ? WIDTH - 1 : ww1);
                const f32x4* p0 = warpf4 + base0 + it * 128 + (cl0 - w0) * 16;
                const f32x4* p1 = warpf4 + base0 + it * 128 + 64 + (cl1 - w0 - 4) * 16;
                asm volatile("global_load_dwordx4 %0, %1, off" : "=v"(F.b0[d]) : "v"(p0));
                asm volatile("global_load_dwordx4 %0, %1, off" : "=v"(F.b1[d]) : "v"(p1));
            }
        }
    };

    auto PROC = [&](int it, Frag& F) {
        const bool edge = (leftw && it == 0) || (rightw && it == NITER - 1);
        if (edge) {
            const int w0 = (rp0 + it) * 8 + px;
            #pragma unroll
            for (int d = 0; d < NOFF; ++d) {
                const int ww0 = w0 + d - 2;
                const int ww1 = ww0 + 4;
                if (ww0 < 0 || ww0 >= WIDTH) F.b0[d] = f32x4{0.f, 0.f, 0.f, 0.f};
                if (ww1 < 0 || ww1 >= WIDTH) F.b1[d] = f32x4{0.f, 0.f, 0.f, 0.f};
            }
        }
        float s0[NOFF], s1[NOFF];
        #pragma unroll
        for (int d = 0; d < NOFF; ++d) {
            const float acc0 = F.a0.x * F.b0[d].x + F.a0.y * F.b0[d].y
                             + F.a0.z * F.b0[d].z + F.a0.w * F.b0[d].w;
            const float acc1 = F.a1.x * F.b1[d].x + F.a1.y * F.b1[d].y
                             + F.a1.z * F.b1[d].z + F.a1.w * F.b1[d].w;
            s0[d] = row_reduce_sum16_lane0(acc0);
            s1[d] = row_reduce_sum16_lane0(acc1);
        }
        const int fb = px * OUTC + c4 * 4;
        rec0w[fb + 0] = F.a0.x; rec0w[fb + 1] = F.a0.y;
        rec0w[fb + 2] = F.a0.z; rec0w[fb + 3] = F.a0.w;
        rec1w[fb + 0] = F.a1.x; rec1w[fb + 1] = F.a1.y;
        rec1w[fb + 2] = F.a1.z; rec1w[fb + 3] = F.a1.w;
        if (c4 == 0) {
            #pragma unroll
            for (int d = 0; d < NOFF; ++d) {
                rec0w[px * OUTC + CH + d] = s0[d] * 0.015625f;
                rec1w[px * OUTC + CH + d] = s1[d] * 0.015625f;
            }
        }
        __builtin_amdgcn_wave_barrier();   // compile-time fence: reads after writes

        const int ob = (pbase + it) * (2 * REC_F4);
        __builtin_nontemporal_store(rec0r[l], &outf4[ob + l]);
        __builtin_nontemporal_store(rec1r[l], &outf4[ob + REC_F4 + l]);
        if (l < REC_F4 - 64) {
            __builtin_nontemporal_store(rec0r[64 + l], &outf4[ob + 64 + l]);
            __builtin_nontemporal_store(rec1r[64 + l], &outf4[ob + REC_F4 + 64 + l]);
        }
        __builtin_amdgcn_wave_barrier();   // next iter's LDS writes stay after these reads
    };

    Frag X, Y;
    LOAD(0, X);
    LOAD(1, Y);
    WAITV(12); PROC(0, X);                // keep: L1(12)
    LOAD(2, X); WAITV(16); PROC(1, Y);    // keep: S0(4)+L2(12)
    LOAD(3, Y); WAITV(16); PROC(2, X);
    LOAD(4, X); WAITV(16); PROC(3, Y);
    LOAD(5, Y); WAITV(16); PROC(4, X);
    LOAD(6, X); WAITV(16); PROC(5, Y);
    LOAD(7, Y); WAITV(16); PROC(6, X);
    WAITV(4);  PROC(7, Y);                // keep: S6(4)
}

extern "C" void kernel_launch(void* const* d_in, const int* in_sizes, int n_in,
                              void* d_out, int out_size, void* d_ws, size_t ws_size,
                              hipStream_t stream) {
    const float* c1   = (const float*)d_in[0];
    const float* warp = (const float*)d_in[1];
    float* out = (float*)d_out;

    StereoCostVolume_kernel<<<NBLOCKS, BDIM, 0, stream>>>(c1, warp, out);
}

// Round 10
// 127.766 us; speedup vs baseline: 1.2152x; 1.1332x over previous
//
#include <hip/hip_runtime.h>

// StereoCostVolume: c1, warp [B=8, H=192, W=640, C=64] f32.
// out [B,H,W,69]: out[...,0:64] = c1; out[...,64+d] = mean_c(c1[w] * warp[w+d-2]), zero-padded in W.
//
// R10: combine R5's TLP (low VGPR -> full occupancy) with R6's ILP (batched
// branch-free loads). One wave = ONE 4-pixel group, single shot, no loop:
//   lane = (px = l>>4, c4 = l&15).
//   - 6 coalesced float4 loads issued back-to-back (1 nt c1 + 5 warp), all
//     branch-free for interior waves (158/160); edge branch is wave-uniform.
//   - 5 dot4 + DPP row_shl 16-lane reductions (VALU pipe, no cross-lane DS).
//   - 1104B record bounced through a private per-wave LDS slice, streamed out
//     as 16B-aligned nt float4 (69 f4: full-wave store + 5-lane tail).
// Live state ~6 f32x4 + addressing -> VGPR ~32-40 => 32 waves/CU (vs 12 at
// R6/R7's VGPR 56-64). In-flight bytes/CU ~ 32 waves x 6KB >> BW*latency.
// Cache policy (R5-R9 evidence: FETCH ~253MB = one input from HBM, other
// L3-resident): nontemporal c1 loads + out stores, plain warp loads.
//
// Decisive test: if this 4th structure also lands ~125us, the limiter is
// aggregate TCC-side traffic (775MB @ ~6.2 TB/s ~= copy ceiling) -> roofline.

typedef float f32x4 __attribute__((ext_vector_type(4)));

#define WIDTH 640
#define CH 64
#define NOFF 5
#define OUTC 69
#define GPX 4                            // pixels per group
#define REC_F4 69                        // float4 per group record (1104 B)
#define NPIX (8 * 192 * 640)             // 983040
#define NGROUPS (NPIX / GPX)             // 245760
#define BDIM 256
#define WPB (BDIM / 64)                  // 4 waves/block
#define NBLOCKS (NGROUPS / WPB)          // 61440
#define GROUPS_PER_ROW (WIDTH / GPX)     // 160

__device__ __forceinline__ float row_reduce_sum16_lane0(float v) {
    union { float f; int i; } a, b;
    a.f = v;
    // row_shl:N (0x100+N): lane i reads lane i+N within its 16-lane row (OOB -> 0).
    b.i = __builtin_amdgcn_update_dpp(0, a.i, 0x101, 0xF, 0xF, true); a.f += b.f;
    b.i = __builtin_amdgcn_update_dpp(0, a.i, 0x102, 0xF, 0xF, true); a.f += b.f;
    b.i = __builtin_amdgcn_update_dpp(0, a.i, 0x104, 0xF, 0xF, true); a.f += b.f;
    b.i = __builtin_amdgcn_update_dpp(0, a.i, 0x108, 0xF, 0xF, true); a.f += b.f;
    return a.f;  // lane 0 of each 16-lane row holds the full 16-lane sum
}

__global__ __launch_bounds__(BDIM) void StereoCostVolume_kernel(
    const float* __restrict__ c1,
    const float* __restrict__ warp,
    float* __restrict__ out)
{
    __shared__ f32x4 lds[WPB * REC_F4];   // 4416 B/block

    const int t   = threadIdx.x;
    const int wid = t >> 6;
    const int l   = t & 63;
    const int px  = l >> 4;
    const int c4  = l & 15;

    const f32x4* c1f4   = (const f32x4*)c1;
    const f32x4* warpf4 = (const f32x4*)warp;
    f32x4*       outf4  = (f32x4*)out;

    const int g   = blockIdx.x * WPB + wid;        // group index == wave index
    const int row = g / GROUPS_PER_ROW;
    const int gw  = g - row * GROUPS_PER_ROW;

    const int base = (g * GPX + px) * 16 + c4;     // f4 idx into c1 AND warp

    // ---- 6 float4 loads, back-to-back ----
    const f32x4 a = __builtin_nontemporal_load(&c1f4[base]);

    f32x4 b[NOFF];
    if (gw != 0 && gw != GROUPS_PER_ROW - 1) {
        // interior (wave-uniform): branch-free, compiler can clause all 5
        #pragma unroll
        for (int d = 0; d < NOFF; ++d)
            b[d] = warpf4[base + (d - 2) * 16];
    } else {
        const int w = gw * GPX + px;
        #pragma unroll
        for (int d = 0; d < NOFF; ++d) {
            const int ww = w + d - 2;
            b[d] = (ww >= 0 && ww < WIDTH) ? warpf4[base + (d - 2) * 16]
                                           : f32x4{0.f, 0.f, 0.f, 0.f};
        }
    }

    // ---- 5 dot4 + 16-lane DPP reductions ----
    float s[NOFF];
    #pragma unroll
    for (int d = 0; d < NOFF; ++d) {
        const float acc = a.x * b[d].x + a.y * b[d].y + a.z * b[d].z + a.w * b[d].w;
        s[d] = row_reduce_sum16_lane0(acc);
    }

    // ---- assemble 1104B record in private per-wave LDS slice ----
    float* rec = (float*)&lds[wid * REC_F4];
    const int fb = px * OUTC + c4 * 4;
    rec[fb + 0] = a.x; rec[fb + 1] = a.y; rec[fb + 2] = a.z; rec[fb + 3] = a.w;
    if (c4 == 0) {
        #pragma unroll
        for (int d = 0; d < NOFF; ++d)
            rec[px * OUTC + CH + d] = s[d] * 0.015625f;
    }
    __builtin_amdgcn_wave_barrier();   // compile-time fence: reads after writes

    // ---- linear 16B-aligned coalesced store (record base = f4 g*69) ----
    const f32x4* recf4 = (const f32x4*)rec;
    const int ob = g * REC_F4;
    __builtin_nontemporal_store(recf4[l], &outf4[ob + l]);
    if (l < REC_F4 - 64)
        __builtin_nontemporal_store(recf4[64 + l], &outf4[ob + 64 + l]);
}

extern "C" void kernel_launch(void* const* d_in, const int* in_sizes, int n_in,
                              void* d_out, int out_size, void* d_ws, size_t ws_size,
                              hipStream_t stream) {
    const float* c1   = (const float*)d_in[0];
    const float* warp = (const float*)d_in[1];
    float* out = (float*)d_out;

    StereoCostVolume_kernel<<<NBLOCKS, BDIM, 0, stream>>>(c1, warp, out);
}